// Round 5
// baseline (23327.174 us; speedup 1.0000x reference)
//
#include <hip/hip_runtime.h>
#include <hip/hip_bf16.h>

// FARGAN vocoder on MI355X. Sizes fixed by the reference:
#define SS      64
#define NSUB    4
#define LPREV   512
#define NF      193
#define NFRAMES 100
#define BATCH   64
#define RPW     16     // batch rows per workgroup (MFMA M); 1 wave per WG

typedef __attribute__((ext_vector_type(8))) short   short8;   // 8 bf16
typedef __attribute__((ext_vector_type(4))) float   floatx4;  // MFMA C/D

#define WB() __builtin_amdgcn_wave_barrier()

// ---------- scalar helpers ----------
__device__ __forceinline__ float bf2f(unsigned short u) {
    return __uint_as_float(((unsigned int)u) << 16);
}
__device__ __forceinline__ unsigned short f2bf(float x) {
    unsigned int u = __float_as_uint(x);
    return (unsigned short)((u + 0x7fffu + ((u >> 16) & 1u)) >> 16);
}
__device__ __forceinline__ unsigned int packbf(float a, float b) {
    return (unsigned int)f2bf(a) | ((unsigned int)f2bf(b) << 16);
}
__device__ __forceinline__ float fsig(float x) { return 1.0f / (1.0f + __expf(-x)); }
__device__ __forceinline__ float ftanh(float x) {
    float e = __expf(-2.0f * fabsf(x));
    float t = 1.0f - 2.0f * e / (1.0f + e);
    return copysignf(t, x);
}
__device__ __forceinline__ float ld1f(int f32, const void* p, size_t i) {
    if (f32) return ((const float*)p)[i];
    return bf2f(((const unsigned short*)p)[i]);
}

__device__ __forceinline__ floatx4 mf(short8 a, short8 b, floatx4 c) {
    return __builtin_amdgcn_mfma_f32_16x16x32_bf16(a, b, c, 0, 0, 0);
}

// A-fragment from packed-bf16 LDS buffer (rows 16B-aligned, strideU mult of 4)
__device__ __forceinline__ short8 ldA(const unsigned short* buf, int strideU,
                                      int m, int kb, int q) {
    const unsigned int* p = (const unsigned int*)buf + m * strideU + kb * 16 + q * 4;
    uint4 u = *(const uint4*)p;
    return __builtin_bit_cast(short8, u);
}
// B-fragment from prepacked weight buffer
__device__ __forceinline__ short8 ldB(const uint4* __restrict__ w, int idx) {
    return __builtin_bit_cast(short8, w[idx]);
}

// ---------- wbuf layout (units = 16B frags) ----------
// frag(seg, tile, kb, lane) at base + (tile*KB + kb)*64 + lane,
// lane = 16*lq + ln holds W[row = rowOff + tile*16 + ln][k = kb*32 + lq*8 .. +7]
#define OFF_FW   0        // 4t x 13kb
#define OFF_FWG  3328     // 4t x 2kb
#define OFF_GRU(G) (3840 + 4608*(G))   // r@+0(6kb) z@+1536(6kb) i@+3072(4kb) h@+4096(2kb)
#define OFF_WG(G)  (17664 + 512*(G))   // 4t x 2kb
#define OFF_SD   19200    // 8t x 10kb
#define OFF_SG   24320    // 8t x 4kb
#define OFF_OUT  26368    // 4t x 4kb
#define NFRAG    27392

// ---------- dtype detector ----------
__global__ void fargan_detect(const void* feats, int* flag) {
    const float* pf = (const float*)feats;
    int ok = 1;
    for (int f = 0; f < 50; ++f) {
        float v = pf[192 * NFRAMES + f];
        if (!(v >= 63.0f && v <= 301.0f)) { ok = 0; break; }
    }
    *flag = ok;   // 1 = fp32, 0 = bf16
}

// ---------- weight prep: repack all seq weights into frag order ----------
__global__ __launch_bounds__(256) void fargan_prep(
    const int* __restrict__ flag,
    const void* Wfw, const void* Wfwg,
    const void* Wih1, const void* Whh1, const void* Wih2, const void* Whh2,
    const void* Wih3, const void* Whh3,
    const void* Wg1, const void* Wg2, const void* Wg3,
    const void* Wsg, const void* Wsd, const void* Wout,
    uint4* __restrict__ wbuf)
{
    int fi = blockIdx.x * 256 + threadIdx.x;
    if (fi >= NFRAG) return;
    int f32 = *flag;
    const void* mats[14] = {Wfw, Wfwg, Wih1, Whh1, Wih2, Whh2, Wih3, Whh3,
                            Wg1, Wg2, Wg3, Wsg, Wsd, Wout};
    const int NSEG = 20;
    const int sb[NSEG]  = {0,3328, 3840,5376,6912,7936, 8448,9984,11520,12544,
                           13056,14592,16128,17152, 17664,18176,18688, 19200,24320,26368};
    const int sa[NSEG]  = {0,1, 2,2,2,3, 4,4,4,5, 6,6,6,7, 8,9,10, 12,11,13};
    const int sbx[NSEG] = {-1,-1, 3,3,-1,-1, 5,5,-1,-1, 7,7,-1,-1, -1,-1,-1, -1,-1,-1};
    const int sro[NSEG] = {0,0, 0,64,128,128, 0,64,128,128, 0,64,128,128, 0,0,0, 0,0,0};
    const int skb[NSEG] = {13,2, 6,6,4,2, 6,6,4,2, 6,6,4,2, 2,2,2, 10,4,4};
    const int ska[NSEG] = {388,64, 128,128,128,64, 128,128,128,64, 128,128,128,64,
                           64,64,64, 320,128,128};
    const int skr[NSEG] = {388,64, 192,192,128,64, 192,192,128,64, 192,192,128,64,
                           64,64,64, 320,128,128};
    int s = 0;
    for (int i = 1; i < NSEG; ++i) if (fi >= sb[i]) s = i;
    int local = fi - sb[s];
    int ln = local & 15, lq = (local >> 4) & 3, tkb = local >> 6;
    int KB = skb[s];
    int kb = tkb % KB, tile = tkb / KB;
    int row = sro[s] + tile * 16 + ln;
    int Ka = ska[s], Kr = skr[s];
    union { unsigned short h[8]; uint4 v; } u;
#pragma unroll
    for (int j = 0; j < 8; ++j) {
        int k = kb * 32 + lq * 8 + j;
        unsigned short val = 0;
        if (k < Kr) {
            const void* m; size_t off;
            if (sbx[s] >= 0 && k >= Ka) { m = mats[sbx[s]]; off = (size_t)row * 64 + (k - Ka); }
            else                        { m = mats[sa[s]];  off = (size_t)row * Ka + k; }
            val = f32 ? f2bf(((const float*)m)[off]) : ((const unsigned short*)m)[off];
        }
        u.h[j] = val;
    }
    wbuf[fi] = u.v;
}

// ---------- kernel 1: frame conv (parallel over B x FRAMES) ----------
template<bool F32>
__device__ __forceinline__ float dot_rt(const void* W, int off, const float* x, int nelem) {
    if constexpr (F32) {
        const float* w = (const float*)W + off;
        float a0 = 0.f, a1 = 0.f;
#pragma unroll 8
        for (int k = 0; k < nelem / 2; ++k) {
            a0 = fmaf(w[2 * k + 0], x[2 * k + 0], a0);
            a1 = fmaf(w[2 * k + 1], x[2 * k + 1], a1);
        }
        return a0 + a1;
    } else {
        const unsigned int* w2 = (const unsigned int*)((const unsigned short*)W + off);
        float a0 = 0.f, a1 = 0.f;
#pragma unroll 8
        for (int k = 0; k < nelem / 2; ++k) {
            unsigned int u = w2[k];
            a0 = fmaf(__uint_as_float(u << 16),          x[2 * k + 0], a0);
            a1 = fmaf(__uint_as_float(u & 0xffff0000u), x[2 * k + 1], a1);
        }
        return a0 + a1;
    }
}

template<bool F32>
__device__ __forceinline__ void conv_body(
    const void* __restrict__ feats, const void* __restrict__ gfeat,
    const void* __restrict__ Wc1, const void* __restrict__ Wc2,
    const void* __restrict__ Wc3, float* __restrict__ cbuf)
{
    int blk = blockIdx.x;
    int b = blk / NFRAMES, f = blk - b * NFRAMES;
    int t = threadIdx.x;
    __shared__ float xa[256], xb[256];

    float v;
    if (t < 192) v = ld1f(F32 ? 1 : 0, feats, (size_t)b * (NF * NFRAMES) + t * NFRAMES + f);
    else         v = ld1f(F32 ? 1 : 0, gfeat, (size_t)b * 64 + (t - 192));
    xa[t] = v;
    __syncthreads();

    float acc = dot_rt<F32>(Wc1, t * 256, xa, 256);
    xb[t] = tanhf(acc);
    __syncthreads();

    acc = dot_rt<F32>(Wc2, t * 256, xb, 256);
    xa[t] = tanhf(acc);
    __syncthreads();

    float a0 = dot_rt<F32>(Wc3, t * 256, xa, 256);
    float a1 = dot_rt<F32>(Wc3, (t + 256) * 256, xa, 256);
    float* co = cbuf + ((size_t)b * NFRAMES + f) * 512;
    // transposed: element e (= j*4+k) -> co[k*128 + j]
    int e0 = t, e1 = t + 256;
    co[(e0 & 3) * 128 + (e0 >> 2)] = tanhf(a0);
    co[(e1 & 3) * 128 + (e1 >> 2)] = tanhf(a1);
}

__global__ __launch_bounds__(256) void fargan_conv(
    const void* feats, const void* gfeat,
    const void* Wc1, const void* Wc2, const void* Wc3,
    const int* flag, float* cbuf)
{
    if (*flag) conv_body<true>(feats, gfeat, Wc1, Wc2, Wc3, cbuf);
    else       conv_body<false>(feats, gfeat, Wc1, Wc2, Wc3, cbuf);
}

// ---------- kernel 2: sequential recurrence ----------
// ONE WAVE per 16 batch rows; full N per wave; zero barriers in the step loop.
// B-frags stream from wbuf (L2-resident, coalesced b128, no dependencies).

__global__ __launch_bounds__(64, 1) void fargan_seq(
    const void* __restrict__ feats, const void* __restrict__ prev_in,
    const int* __restrict__ flag, const float* __restrict__ cbuf,
    const uint4* __restrict__ wbuf, void* __restrict__ outp)
{
    const int t = threadIdx.x;              // lane 0..63
    const int b0 = blockIdx.x * RPW;
    const int ln = t & 15, lq = t >> 4;
    const int f32 = *flag;

    __shared__ __align__(16) unsigned short hist[RPW * 520];  // bf16 ring (512 used)
    __shared__ __align__(16) unsigned short catb[RPW * 424];  // fw input K=388(+pad)
    __shared__ __align__(16) unsigned short xg  [RPW * 200];  // [in0|ps|s](+pad)
    __shared__ __align__(16) unsigned short svp [RPW * 72];   // s_new staging
    __shared__ __align__(16) unsigned short vpb [RPW * 72];   // vpre staging
    __shared__ __align__(16) unsigned short skx [RPW * 328];  // [o1|o2|o3|fw|ps](+pad)
    __shared__ __align__(16) unsigned short sdb [RPW * 136];
    __shared__ __align__(16) unsigned short sob [RPW * 136];
    __shared__ int periods[RPW];

    // one-time zero init (covers K pads) + hist fill
    for (int i = t; i < RPW * 424; i += 64) catb[i] = 0;
    for (int i = t; i < RPW * 200; i += 64) xg[i] = 0;
    for (int i = t; i < RPW * 72;  i += 64) { svp[i] = 0; vpb[i] = 0; }
    for (int i = t; i < RPW * 328; i += 64) skx[i] = 0;
    for (int i = t; i < RPW * 136; i += 64) { sdb[i] = 0; sob[i] = 0; }
    for (int i = t; i < RPW * 512; i += 64) {
        int r = i >> 9, c = i & 511;
        hist[r * 520 + c] = f2bf(ld1f(f32, prev_in, (size_t)(b0 + r) * LPREV + c));
    }
    floatx4 sv[3][4];
#pragma unroll
    for (int G = 0; G < 3; ++G)
#pragma unroll
        for (int tl = 0; tl < 4; ++tl) sv[G][tl] = (floatx4){0.f, 0.f, 0.f, 0.f};
    WB();

    const floatx4 z4 = {0.f, 0.f, 0.f, 0.f};
    int base = 0;
    for (int f = 0; f < NFRAMES; ++f) {
        if (t < RPW)
            periods[t] = (int)rintf(ld1f(f32, feats,
                (size_t)(b0 + t) * (NF * NFRAMES) + (NF - 1) * NFRAMES + f));
        WB();

        for (int kk = 0; kk < NSUB; ++kk) {
            // ---------- BUILD (row = t>>2, quarter = t&3) ----------
            {
                int row = t >> 2, q4 = t & 3;
                const float* crow = cbuf + ((size_t)(b0 + row) * NFRAMES + f) * 512 + kk * 128;
                unsigned int* cat32 = (unsigned int*)catb;
                int cb = row * 212;
#pragma unroll
                for (int i = 0; i < 16; ++i) {
                    int ui = q4 * 16 + i;
                    unsigned int old = cat32[cb + ui];        // old feat2s
                    cat32[cb + 130 + ui] = old;               // -> sfw slot [260:388)
                    cat32[cb + ui] = packbf(crow[2 * ui], crow[2 * ui + 1]);
                }
                int hb = row * 520;
#pragma unroll
                for (int i = 0; i < 16; ++i) {
                    int n = q4 * 16 + i;
                    unsigned short h = hist[hb + ((base + 448 + n) & 511)];
                    catb[row * 424 + 128 + n] = h;            // prev_sub
                    skx [row * 328 + 256 + n] = h;
                    xg  [row * 200 + 64  + n] = h;
                }
                int per = periods[row];
#pragma unroll
                for (int i = 0; i < 17; ++i) {
                    int n = q4 * 17 + i;
                    int idx = 512 - per + n - 2;
                    if (idx >= 512) idx -= per;
                    catb[row * 424 + 192 + n] = hist[hb + ((base + idx) & 511)];
                }
            }
            WB();

            // ---------- FW: vpre = tanh(cat @ Wfw.T) ----------
            floatx4 vpv[4];
            {
                short8 A13[13];
#pragma unroll
                for (int kb = 0; kb < 13; ++kb) A13[kb] = ldA(catb, 212, ln, kb, lq);
                floatx4 C[4] = {z4, z4, z4, z4};
#pragma unroll
                for (int kb = 0; kb < 13; ++kb)
#pragma unroll
                    for (int tl = 0; tl < 4; ++tl)
                        C[tl] = mf(A13[kb], ldB(wbuf, OFF_FW + (tl * 13 + kb) * 64 + t), C[tl]);
#pragma unroll
                for (int tl = 0; tl < 4; ++tl)
#pragma unroll
                    for (int r = 0; r < 4; ++r) {
                        float v = ftanh(C[tl][r]);
                        vpv[tl][r] = v;
                        vpb[(4 * lq + r) * 72 + tl * 16 + ln] = f2bf(v);
                    }
            }
            WB();

            // ---------- FWG: fw = vpre * sig(vpre @ Wfwg.T) ----------
            {
                short8 Ag[2];
#pragma unroll
                for (int kb = 0; kb < 2; ++kb) Ag[kb] = ldA(vpb, 36, ln, kb, lq);
                floatx4 C[4] = {z4, z4, z4, z4};
#pragma unroll
                for (int kb = 0; kb < 2; ++kb)
#pragma unroll
                    for (int tl = 0; tl < 4; ++tl)
                        C[tl] = mf(Ag[kb], ldB(wbuf, OFF_FWG + (tl * 2 + kb) * 64 + t), C[tl]);
#pragma unroll
                for (int tl = 0; tl < 4; ++tl)
#pragma unroll
                    for (int r = 0; r < 4; ++r) {
                        unsigned short ob = f2bf(vpv[tl][r] * fsig(C[tl][r]));
                        skx[(4 * lq + r) * 328 + 192 + tl * 16 + ln] = ob;
                        xg [(4 * lq + r) * 200 + tl * 16 + ln] = ob;  // in0 for GRU1
                    }
            }
            WB();

            // ---------- GRU + GLU x3 ----------
#pragma unroll
            for (int G = 0; G < 3; ++G) {
                const int OR = OFF_GRU(G), OZ = OR + 1536, OI = OR + 3072, OH = OR + 4096;
                // stage s into xg k-slot [128:192)
#pragma unroll
                for (int tl = 0; tl < 4; ++tl)
#pragma unroll
                    for (int r = 0; r < 4; ++r)
                        xg[(4 * lq + r) * 200 + 128 + tl * 16 + ln] = f2bf(sv[G][tl][r]);
                WB();
                {
                    short8 Ax[6];
#pragma unroll
                    for (int kb = 0; kb < 6; ++kb) Ax[kb] = ldA(xg, 100, ln, kb, lq);
                    floatx4 Cr[4] = {z4, z4, z4, z4}, Cz[4] = {z4, z4, z4, z4};
                    floatx4 Ci[4] = {z4, z4, z4, z4}, Ch[4] = {z4, z4, z4, z4};
#pragma unroll
                    for (int kb = 0; kb < 6; ++kb)
#pragma unroll
                        for (int tl = 0; tl < 4; ++tl) {
                            Cr[tl] = mf(Ax[kb], ldB(wbuf, OR + (tl * 6 + kb) * 64 + t), Cr[tl]);
                            Cz[tl] = mf(Ax[kb], ldB(wbuf, OZ + (tl * 6 + kb) * 64 + t), Cz[tl]);
                            if (kb < 4)
                                Ci[tl] = mf(Ax[kb], ldB(wbuf, OI + (tl * 4 + kb) * 64 + t), Ci[tl]);
                            else
                                Ch[tl] = mf(Ax[kb], ldB(wbuf, OH + (tl * 2 + (kb - 4)) * 64 + t), Ch[tl]);
                        }
#pragma unroll
                    for (int tl = 0; tl < 4; ++tl)
#pragma unroll
                        for (int r = 0; r < 4; ++r) {
                            float rr = fsig(Cr[tl][r]);
                            float zz = fsig(Cz[tl][r]);
                            float nn = ftanh(Ci[tl][r] + rr * Ch[tl][r]);
                            float sn = (1.0f - zz) * nn + zz * sv[G][tl][r];
                            sv[G][tl][r] = sn;
                            svp[(4 * lq + r) * 72 + tl * 16 + ln] = f2bf(sn);
                        }
                }
                WB();
                // GLU: o = s * sig(s @ Wg.T)
                {
                    short8 As[2];
#pragma unroll
                    for (int kb = 0; kb < 2; ++kb) As[kb] = ldA(svp, 36, ln, kb, lq);
                    floatx4 C[4] = {z4, z4, z4, z4};
#pragma unroll
                    for (int kb = 0; kb < 2; ++kb)
#pragma unroll
                        for (int tl = 0; tl < 4; ++tl)
                            C[tl] = mf(As[kb], ldB(wbuf, OFF_WG(G) + (tl * 2 + kb) * 64 + t), C[tl]);
#pragma unroll
                    for (int tl = 0; tl < 4; ++tl)
#pragma unroll
                        for (int r = 0; r < 4; ++r) {
                            unsigned short ob = f2bf(sv[G][tl][r] * fsig(C[tl][r]));
                            skx[(4 * lq + r) * 328 + G * 64 + tl * 16 + ln] = ob;
                            if (G < 2) xg[(4 * lq + r) * 200 + tl * 16 + ln] = ob;
                        }
                }
                WB();
            }

            // ---------- SD: sd = tanh(skx @ Wsd.T), N=128 ----------
            floatx4 sdv[8];
            {
                short8 Ak[10];
#pragma unroll
                for (int kb = 0; kb < 10; ++kb) Ak[kb] = ldA(skx, 164, ln, kb, lq);
                floatx4 C[8] = {z4, z4, z4, z4, z4, z4, z4, z4};
#pragma unroll
                for (int kb = 0; kb < 10; ++kb)
#pragma unroll
                    for (int tl = 0; tl < 8; ++tl)
                        C[tl] = mf(Ak[kb], ldB(wbuf, OFF_SD + (tl * 10 + kb) * 64 + t), C[tl]);
#pragma unroll
                for (int tl = 0; tl < 8; ++tl)
#pragma unroll
                    for (int r = 0; r < 4; ++r) {
                        float v = ftanh(C[tl][r]);
                        sdv[tl][r] = v;
                        sdb[(4 * lq + r) * 136 + tl * 16 + ln] = f2bf(v);
                    }
            }
            WB();

            // ---------- SG: so = sd * sig(sd @ Wsg.T) ----------
            {
                short8 Ak[4];
#pragma unroll
                for (int kb = 0; kb < 4; ++kb) Ak[kb] = ldA(sdb, 68, ln, kb, lq);
                floatx4 C[8] = {z4, z4, z4, z4, z4, z4, z4, z4};
#pragma unroll
                for (int kb = 0; kb < 4; ++kb)
#pragma unroll
                    for (int tl = 0; tl < 8; ++tl)
                        C[tl] = mf(Ak[kb], ldB(wbuf, OFF_SG + (tl * 4 + kb) * 64 + t), C[tl]);
#pragma unroll
                for (int tl = 0; tl < 8; ++tl)
#pragma unroll
                    for (int r = 0; r < 4; ++r)
                        sob[(4 * lq + r) * 136 + tl * 16 + ln] = f2bf(sdv[tl][r] * fsig(C[tl][r]));
            }
            WB();

            // ---------- OUT: ov = tanh(so @ Wout.T) ----------
            {
                short8 Ak[4];
#pragma unroll
                for (int kb = 0; kb < 4; ++kb) Ak[kb] = ldA(sob, 68, ln, kb, lq);
                floatx4 C[4] = {z4, z4, z4, z4};
#pragma unroll
                for (int kb = 0; kb < 4; ++kb)
#pragma unroll
                    for (int tl = 0; tl < 4; ++tl)
                        C[tl] = mf(Ak[kb], ldB(wbuf, OFF_OUT + (tl * 4 + kb) * 64 + t), C[tl]);
#pragma unroll
                for (int tl = 0; tl < 4; ++tl)
#pragma unroll
                    for (int r = 0; r < 4; ++r) {
                        float ov = ftanh(C[tl][r]);
                        int m = 4 * lq + r, n = tl * 16 + ln;
                        hist[m * 520 + ((base + n) & 511)] = f2bf(ov);
                        size_t oi = (size_t)(b0 + m) * (NFRAMES * NSUB * SS)
                                  + f * (NSUB * SS) + kk * SS + n;
                        if (f32) ((float*)outp)[oi] = ov;
                        else     ((unsigned short*)outp)[oi] = f2bf(ov);
                    }
            }
            WB();

            base += SS;
        }
    }
}

// ---------- launch ----------
extern "C" void kernel_launch(void* const* d_in, const int* in_sizes, int n_in,
                              void* d_out, int out_size, void* d_ws, size_t ws_size,
                              hipStream_t stream) {
    const void* feats = d_in[0];
    const void* gfeat = d_in[1];
    const void* prev  = d_in[2];
    const void* Wc1   = d_in[3];
    const void* Wc2   = d_in[4];
    const void* Wc3   = d_in[5];
    const void* Wfw   = d_in[6];
    const void* Wfwg  = d_in[7];
    const void* Wih1  = d_in[8];
    const void* Whh1  = d_in[9];
    const void* Wih2  = d_in[10];
    const void* Whh2  = d_in[11];
    const void* Wih3  = d_in[12];
    const void* Whh3  = d_in[13];
    const void* Wg1   = d_in[14];
    const void* Wg2   = d_in[15];
    const void* Wg3   = d_in[16];
    const void* Wsg   = d_in[17];
    const void* Wsd   = d_in[18];
    const void* Wout  = d_in[19];

    int*   flag = (int*)d_ws;                                    // 1 int @ 0
    float* cbuf = (float*)((char*)d_ws + 256);                   // 13,107,200 B
    uint4* wbuf = (uint4*)((char*)d_ws + 256 + 13107200);        // 438,272 B

    fargan_detect<<<1, 1, 0, stream>>>(feats, flag);
    fargan_prep<<<(NFRAG + 255) / 256, 256, 0, stream>>>(flag, Wfw, Wfwg,
        Wih1, Whh1, Wih2, Whh2, Wih3, Whh3, Wg1, Wg2, Wg3, Wsg, Wsd, Wout, wbuf);
    fargan_conv<<<BATCH * NFRAMES, 256, 0, stream>>>(feats, gfeat, Wc1, Wc2, Wc3, flag, cbuf);
    fargan_seq<<<BATCH / RPW, 64, 0, stream>>>(feats, prev, flag, cbuf, wbuf, d_out);
}

// Round 6
// 3394.058 us; speedup vs baseline: 6.8729x; 6.8729x over previous
//
#include <hip/hip_runtime.h>
#include <hip/hip_bf16.h>

// FARGAN vocoder on MI355X. Sizes fixed by the reference:
#define SS      64
#define NSUB    4
#define LPREV   512
#define NF      193
#define NFRAMES 100
#define BATCH   64
#define RPW     16     // batch rows per workgroup (MFMA M)

typedef __attribute__((ext_vector_type(8))) short   short8;   // 8 bf16 (4 VGPRs)
typedef __attribute__((ext_vector_type(4))) float   floatx4;  // MFMA C/D

// ---------- scalar helpers ----------
__device__ __forceinline__ float bf2f(unsigned short u) {
    return __uint_as_float(((unsigned int)u) << 16);
}
__device__ __forceinline__ unsigned short f2bf(float x) {
    unsigned int u = __float_as_uint(x);
    return (unsigned short)((u + 0x7fffu + ((u >> 16) & 1u)) >> 16);
}
__device__ __forceinline__ unsigned int packbf(float a, float b) {
    return (unsigned int)f2bf(a) | ((unsigned int)f2bf(b) << 16);
}
__device__ __forceinline__ float fsig(float x) { return 1.0f / (1.0f + __expf(-x)); }
__device__ __forceinline__ float ftanh(float x) {
    float e = __expf(-2.0f * fabsf(x));         // in (0,1], no overflow
    float t = 1.0f - 2.0f * e / (1.0f + e);
    return copysignf(t, x);
}
__device__ __forceinline__ float ld1f(int f32, const void* p, size_t i) {
    if (f32) return ((const float*)p)[i];
    return bf2f(((const unsigned short*)p)[i]);
}
__device__ __forceinline__ float lo16(unsigned int u) { return __uint_as_float(u << 16); }
__device__ __forceinline__ float hi16(unsigned int u) { return __uint_as_float(u & 0xffff0000u); }

// MFMA wrapper
__device__ __forceinline__ floatx4 mf(short8 a, short8 b, floatx4 c) {
    return __builtin_amdgcn_mfma_f32_16x16x32_bf16(a, b, c, 0, 0, 0);
}

// B-fragment preload: lane needs W[n][k0..k0+7] as 8 bf16 (zeros past realK).
__device__ __forceinline__ short8 ldfrag(int f32, const void* W, int Kdim, int realK,
                                         int n, int k0) {
    union { unsigned short h[8]; short8 s; } u;
#pragma unroll
    for (int i = 0; i < 8; ++i) {
        int k = k0 + i;
        unsigned short v = 0;
        if (k < realK)
            v = f32 ? f2bf(((const float*)W)[(size_t)n * Kdim + k])
                    : ((const unsigned short*)W)[(size_t)n * Kdim + k];
        u.h[i] = v;
    }
    return u.s;
}

// A-fragment from packed-bf16 LDS buffer: row m, k-block kb, quad q.
__device__ __forceinline__ short8 ldA(const unsigned short* buf, int strideU,
                                      int m, int kb, int q) {
    const unsigned int* p = (const unsigned int*)buf + m * strideU + kb * 16 + q * 4;
    uint4 u = *(const uint4*)p;
    return __builtin_bit_cast(short8, u);
}

// ---------- dtype detector ----------
// features[0,192,f] (period) in [64,300): 50/50 in-range as fp32 => fp32 inputs.
__global__ void fargan_detect(const void* feats, int* flag) {
    const float* pf = (const float*)feats;
    int ok = 1;
    for (int f = 0; f < 50; ++f) {
        float v = pf[192 * NFRAMES + f];
        if (!(v >= 63.0f && v <= 301.0f)) { ok = 0; break; }
    }
    *flag = ok;
}

// ---------- prep: repack Wc1/2/3 transposed + bf16-pair packed ----------
// wct layout (uints): L1 [k2<128][n<256] @0 ; L2 @32768 ; L3 [k2<128][n<512] @65536
__global__ __launch_bounds__(256) void fargan_prep_conv(
    const int* __restrict__ flag,
    const void* Wc1, const void* Wc2, const void* Wc3,
    unsigned int* __restrict__ wct)
{
    int idx = blockIdx.x * 256 + threadIdx.x;
    if (idx >= 131072) return;
    int f32 = *flag;
    const void* W; int n, k2;
    if (idx < 32768)      { W = Wc1; k2 = idx >> 8, n = idx & 255; }
    else if (idx < 65536) { W = Wc2; k2 = (idx - 32768) >> 8; n = idx & 255; }
    else                  { W = Wc3; k2 = (idx - 65536) >> 9; n = (idx - 65536) & 511; }
    size_t off = (size_t)n * 256 + 2 * k2;
    unsigned int v;
    if (f32) {
        const float* p = (const float*)W + off;
        v = packbf(p[0], p[1]);
    } else {
        v = *(const unsigned int*)((const unsigned short*)W + off);
    }
    wct[idx] = v;
}

// ---------- kernel 1: frame conv (coalesced transposed weights) ----------
template<bool F32>
__device__ __forceinline__ void conv_body(
    const void* __restrict__ feats, const void* __restrict__ gfeat,
    const unsigned int* __restrict__ wct, float* __restrict__ cbuf)
{
    int blk = blockIdx.x;
    int b = blk / NFRAMES, f = blk - b * NFRAMES;
    int t = threadIdx.x;
    __shared__ float xa[256], xb[256];

    float v;
    if (t < 192) v = ld1f(F32 ? 1 : 0, feats, (size_t)b * (NF * NFRAMES) + t * NFRAMES + f);
    else         v = ld1f(F32 ? 1 : 0, gfeat, (size_t)b * 64 + (t - 192));
    xa[t] = v;
    __syncthreads();

    const unsigned int* w1 = wct;
    const unsigned int* w2 = wct + 32768;
    const unsigned int* w3 = wct + 65536;

    float a0 = 0.f, a1 = 0.f;
#pragma unroll 8
    for (int k2 = 0; k2 < 128; ++k2) {
        unsigned int u = w1[k2 * 256 + t];
        a0 = fmaf(lo16(u), xa[2 * k2], a0);
        a1 = fmaf(hi16(u), xa[2 * k2 + 1], a1);
    }
    xb[t] = tanhf(a0 + a1);
    __syncthreads();

    a0 = 0.f; a1 = 0.f;
#pragma unroll 8
    for (int k2 = 0; k2 < 128; ++k2) {
        unsigned int u = w2[k2 * 256 + t];
        a0 = fmaf(lo16(u), xb[2 * k2], a0);
        a1 = fmaf(hi16(u), xb[2 * k2 + 1], a1);
    }
    xa[t] = tanhf(a0 + a1);
    __syncthreads();

    a0 = 0.f; a1 = 0.f;
    float b0 = 0.f, b1 = 0.f;
#pragma unroll 8
    for (int k2 = 0; k2 < 128; ++k2) {
        unsigned int u = w3[k2 * 512 + t];
        unsigned int u2 = w3[k2 * 512 + t + 256];
        a0 = fmaf(lo16(u),  xa[2 * k2],     a0);
        a1 = fmaf(hi16(u),  xa[2 * k2 + 1], a1);
        b0 = fmaf(lo16(u2), xa[2 * k2],     b0);
        b1 = fmaf(hi16(u2), xa[2 * k2 + 1], b1);
    }
    float* co = cbuf + ((size_t)b * NFRAMES + f) * 512;
    // transposed: element e (= j*4+k) -> co[k*128 + j]
    int e0 = t, e1 = t + 256;
    co[(e0 & 3) * 128 + (e0 >> 2)] = tanhf(a0 + a1);
    co[(e1 & 3) * 128 + (e1 >> 2)] = tanhf(b0 + b1);
}

__global__ __launch_bounds__(256) void fargan_conv(
    const void* feats, const void* gfeat,
    const int* flag, const unsigned int* wct, float* cbuf)
{
    if (*flag) conv_body<true>(feats, gfeat, wct, cbuf);
    else       conv_body<false>(feats, gfeat, wct, cbuf);
}

// ---------- kernel 2: sequential recurrence (MFMA, resident weights) ----------
// 4 WGs x 16 batch rows, 4 waves n-split. GRU states in C-layout registers;
// crow/period prefetched one step/frame ahead.

__global__ __launch_bounds__(256, 1) void fargan_seq(
    const void* __restrict__ feats, const void* __restrict__ prev_in,
    const void* __restrict__ Wfw,  const void* __restrict__ Wfwg,
    const void* __restrict__ Wih1, const void* __restrict__ Whh1,
    const void* __restrict__ Wih2, const void* __restrict__ Whh2,
    const void* __restrict__ Wih3, const void* __restrict__ Whh3,
    const void* __restrict__ Wg1,  const void* __restrict__ Wg2,
    const void* __restrict__ Wg3,
    const void* __restrict__ Wsg,  const void* __restrict__ Wsd,
    const void* __restrict__ Wout,
    const int* __restrict__ flag, const float* __restrict__ cbuf,
    void* __restrict__ outp)
{
    const int t = threadIdx.x;
    const int b0 = blockIdx.x * RPW;
    const int lane = t & 63, w = t >> 6;
    const int lq = lane >> 4, ln = lane & 15;
    const int nj = 16 * w + ln;            // n for 64-wide layers
    const int f32 = *flag;

    // ---- LDS ----
    __shared__ __align__(16) unsigned short hist[RPW * 520];   // bf16 ring, mod-512
    __shared__ __align__(16) unsigned short catb[RPW * 424];   // [feat2s|ps|look|sfw|0pad]
    __shared__ __align__(16) unsigned short xg  [RPW * 200];   // [in0|ps|s]
    __shared__ __align__(16) unsigned short skx [RPW * 328];   // [o1|o2|o3|fw|ps]
    __shared__ __align__(16) unsigned short sdbb[RPW * 136];
    __shared__ __align__(16) unsigned short sobb[RPW * 136];
    __shared__ __align__(16) unsigned short vpre[RPW * 72];
    __shared__ __align__(16) unsigned short svp [RPW * 72];    // packed s_new
    __shared__ __align__(16) unsigned short wsd[128 * 328];    // Wsd, 164u stride
    __shared__ int period_s[RPW];

    // ---- resident B-fragments (per lane) ----
    short8 Bfw[13], Bfwg[2], Bout[4];
    short8 Br[3][6], Bz[3][6], Bi[3][4], Bh[3][2], Bg[3][2];
    short8 Bsg[2][4];

    const void* WihA[3] = {Wih1, Wih2, Wih3};
    const void* WhhA[3] = {Whh1, Whh2, Whh3};
    const void* WgA[3]  = {Wg1,  Wg2,  Wg3};

#pragma unroll
    for (int kb = 0; kb < 13; ++kb) Bfw[kb] = ldfrag(f32, Wfw, 388, 388, nj, kb * 32 + lq * 8);
#pragma unroll
    for (int kb = 0; kb < 2; ++kb)  Bfwg[kb] = ldfrag(f32, Wfwg, 64, 64, nj, kb * 32 + lq * 8);
#pragma unroll
    for (int G = 0; G < 3; ++G) {
#pragma unroll
        for (int kb = 0; kb < 4; ++kb) {
            Br[G][kb] = ldfrag(f32, WihA[G], 128, 128, nj,       kb * 32 + lq * 8);
            Bz[G][kb] = ldfrag(f32, WihA[G], 128, 128, 64 + nj,  kb * 32 + lq * 8);
            Bi[G][kb] = ldfrag(f32, WihA[G], 128, 128, 128 + nj, kb * 32 + lq * 8);
        }
#pragma unroll
        for (int kb = 0; kb < 2; ++kb) {
            Br[G][4 + kb] = ldfrag(f32, WhhA[G], 64, 64, nj,       kb * 32 + lq * 8);
            Bz[G][4 + kb] = ldfrag(f32, WhhA[G], 64, 64, 64 + nj,  kb * 32 + lq * 8);
            Bh[G][kb]     = ldfrag(f32, WhhA[G], 64, 64, 128 + nj, kb * 32 + lq * 8);
            Bg[G][kb]     = ldfrag(f32, WgA[G],  64, 64, nj,       kb * 32 + lq * 8);
        }
    }
#pragma unroll
    for (int tile = 0; tile < 2; ++tile)
#pragma unroll
        for (int kb = 0; kb < 4; ++kb)
            Bsg[tile][kb] = ldfrag(f32, Wsg, 128, 128, 32 * w + tile * 16 + ln, kb * 32 + lq * 8);
#pragma unroll
    for (int kb = 0; kb < 4; ++kb) Bout[kb] = ldfrag(f32, Wout, 128, 128, nj, kb * 32 + lq * 8);

    // ---- Wsd -> LDS (164u stride rows; zeros past K=320) ----
    {
        int rr = t >> 1, half = t & 1;
        for (int c = half * 82; c < half * 82 + 82; ++c) {
            int k0 = 2 * c;
            unsigned int v = 0;
            if (k0 < 320) {
                if (f32) {
                    const float* p = (const float*)Wsd + (size_t)rr * 320 + k0;
                    v = packbf(p[0], p[1]);
                } else {
                    v = *(const unsigned int*)((const unsigned short*)Wsd + (size_t)rr * 320 + k0);
                }
            }
            ((unsigned int*)wsd)[rr * 164 + c] = v;
        }
    }

    // ---- zero init LDS state ----
    for (int i = t; i < RPW * 424; i += 256) catb[i] = 0;
    for (int i = t; i < RPW * 200; i += 256) xg[i] = 0;
    for (int i = t; i < RPW * 328; i += 256) skx[i] = 0;
    for (int i = t; i < RPW * 136; i += 256) { sdbb[i] = 0; sobb[i] = 0; }
    for (int i = t; i < RPW * 72;  i += 256) { vpre[i] = 0; svp[i] = 0; }
    for (int i = t; i < RPW * 512; i += 256) {
        int row = i >> 9, c = i & 511;
        hist[row * 520 + c] = f2bf(ld1f(f32, prev_in, (size_t)(b0 + row) * LPREV + c));
    }

    // GRU states in C-layout registers: svr[G][r] = s[row 4lq+r][col nj]
    floatx4 svr[3];
#pragma unroll
    for (int G = 0; G < 3; ++G) svr[G] = (floatx4){0.f, 0.f, 0.f, 0.f};

    // ---- prefetch regs ----
    const int prow = t >> 4, px16 = t & 15, pe8 = (t & 15) * 8;
    float pfc[8];
    {
        const float* cr0 = cbuf + ((size_t)(b0 + prow) * NFRAMES + 0) * 512 + 0 * 128 + pe8;
#pragma unroll
        for (int i = 0; i < 8; ++i) pfc[i] = cr0[i];
    }
    float pper = 0.f;
    if (t < RPW)
        pper = ld1f(f32, feats, (size_t)(b0 + t) * (NF * NFRAMES) + (NF - 1) * NFRAMES + 0);
    __syncthreads();

    const floatx4 z4 = {0.f, 0.f, 0.f, 0.f};
    int base = 0;
    for (int f = 0; f < NFRAMES; ++f) {
        if (t < RPW) period_s[t] = (int)rintf(pper);
        __syncthreads();
        if (t < RPW) {
            int fN = (f + 1 < NFRAMES) ? f + 1 : f;
            pper = ld1f(f32, feats, (size_t)(b0 + t) * (NF * NFRAMES) + (NF - 1) * NFRAMES + fN);
        }

        for (int kk = 0; kk < NSUB; ++kk) {
            // ================= BUILD =================
            {
                int row = prow;
                unsigned int* cat32 = (unsigned int*)catb;
                int cb = row * 212;
                int e8 = pe8;
                // old feat2s -> sfw slot [260:388)
                unsigned int o0 = cat32[cb + (e8 >> 1) + 0];
                unsigned int o1 = cat32[cb + (e8 >> 1) + 1];
                unsigned int o2 = cat32[cb + (e8 >> 1) + 2];
                unsigned int o3 = cat32[cb + (e8 >> 1) + 3];
                cat32[cb + 130 + (e8 >> 1) + 0] = o0;
                cat32[cb + 130 + (e8 >> 1) + 1] = o1;
                cat32[cb + 130 + (e8 >> 1) + 2] = o2;
                cat32[cb + 130 + (e8 >> 1) + 3] = o3;
                cat32[cb + (e8 >> 1) + 0] = packbf(pfc[0], pfc[1]);
                cat32[cb + (e8 >> 1) + 1] = packbf(pfc[2], pfc[3]);
                cat32[cb + (e8 >> 1) + 2] = packbf(pfc[4], pfc[5]);
                cat32[cb + (e8 >> 1) + 3] = packbf(pfc[6], pfc[7]);
                // prefetch next step's crow (consumed next BUILD)
                {
                    int sN = f * 4 + kk + 1;
                    if (sN > NFRAMES * 4 - 1) sN = NFRAMES * 4 - 1;
                    int fN = sN >> 2, kN = sN & 3;
                    const float* nc = cbuf + ((size_t)(b0 + row) * NFRAMES + fN) * 512
                                    + kN * 128 + e8;
#pragma unroll
                    for (int i = 0; i < 8; ++i) pfc[i] = nc[i];
                }
                // prev_sub -> cat[128:192), skx[256:320), xg[64:128)
                int i4 = px16 * 4;
#pragma unroll
                for (int ii = 0; ii < 4; ++ii) {
                    int i = i4 + ii;
                    unsigned short h = hist[row * 520 + ((base + 448 + i) & 511)];
                    catb[row * 424 + 128 + i] = h;
                    skx [row * 328 + 256 + i] = h;
                    xg  [row * 200 + 64  + i] = h;
                }
                // lookback -> cat[192:260)
                int per = period_s[row];
#pragma unroll
                for (int ii = 0; ii < 5; ++ii) {
                    int i = px16 * 5 + ii;
                    if (i < 68) {
                        int idx = LPREV - per + i - 2;
                        if (idx >= LPREV) idx -= per;
                        catb[row * 424 + 192 + i] = hist[row * 520 + ((base + idx) & 511)];
                    }
                }
            }
            __syncthreads();

            // ================= FW (tanh), 2 chains =================
            {
                floatx4 C0 = z4, C1 = z4;
#pragma unroll
                for (int kb = 0; kb < 13; ++kb) {
                    short8 a = ldA(catb, 212, ln, kb, lq);
                    if (kb & 1) C1 = mf(a, Bfw[kb], C1);
                    else        C0 = mf(a, Bfw[kb], C0);
                }
#pragma unroll
                for (int r = 0; r < 4; ++r) {
                    int m = 4 * lq + r;
                    vpre[m * 72 + nj] = f2bf(ftanh(C0[r] + C1[r]));
                }
            }
            __syncthreads();

            // ================= FWG (glu); also stage sv[0] =================
            {
                floatx4 C = z4;
#pragma unroll
                for (int kb = 0; kb < 2; ++kb)
                    C = mf(ldA(vpre, 36, ln, kb, lq), Bfwg[kb], C);
#pragma unroll
                for (int r = 0; r < 4; ++r) {
                    int m = 4 * lq + r;
                    float vp = bf2f(vpre[m * 72 + nj]);
                    unsigned short ob = f2bf(vp * fsig(C[r]));
                    skx[m * 328 + 192 + nj] = ob;   // fw slot
                    xg [m * 200 + nj]       = ob;   // in0 for GRU1
                    xg [m * 200 + 128 + nj] = f2bf(svr[0][r]);   // s for GRU1
                }
            }
            __syncthreads();

            // ================= GRU + GLU x3 =================
#pragma unroll
            for (int G = 0; G < 3; ++G) {
                // GRU dot + in-lane nonlinearity (4 independent chains)
                {
                    floatx4 Cr = z4, Cz = z4, Ci = z4, Ch = z4;
#pragma unroll
                    for (int kb = 0; kb < 6; ++kb) {
                        short8 a = ldA(xg, 100, ln, kb, lq);
                        Cr = mf(a, Br[G][kb], Cr);
                        Cz = mf(a, Bz[G][kb], Cz);
                        if (kb < 4) Ci = mf(a, Bi[G][kb], Ci);
                        else        Ch = mf(a, Bh[G][kb - 4], Ch);
                    }
#pragma unroll
                    for (int r = 0; r < 4; ++r) {
                        int m = 4 * lq + r;
                        float rr = fsig(Cr[r]);
                        float zz = fsig(Cz[r]);
                        float nn = ftanh(Ci[r] + rr * Ch[r]);
                        float sn = (1.0f - zz) * nn + zz * svr[G][r];
                        svr[G][r] = sn;
                        svp[m * 72 + nj] = f2bf(sn);
                    }
                }
                __syncthreads();
                // GLU on s_new; stage next GRU's in0 + s
                {
                    floatx4 C = z4;
#pragma unroll
                    for (int kb = 0; kb < 2; ++kb)
                        C = mf(ldA(svp, 36, ln, kb, lq), Bg[G][kb], C);
#pragma unroll
                    for (int r = 0; r < 4; ++r) {
                        int m = 4 * lq + r;
                        unsigned short ob = f2bf(svr[G][r] * fsig(C[r]));
                        skx[m * 328 + G * 64 + nj] = ob;
                        if (G < 2) {
                            xg[m * 200 + nj]       = ob;                  // in0
                            xg[m * 200 + 128 + nj] = f2bf(svr[G + 1][r]); // s
                        }
                    }
                }
                __syncthreads();
            }

            // ================= SD (tanh), B from LDS, 4 chains =================
            {
                floatx4 C00 = z4, C01 = z4, C10 = z4, C11 = z4;
                int n0 = 32 * w + ln, n1 = n0 + 16;
#pragma unroll
                for (int kb = 0; kb < 10; ++kb) {
                    short8 a   = ldA(skx, 164, ln, kb, lq);
                    short8 b0f = ldA(wsd, 164, n0, kb, lq);
                    short8 b1f = ldA(wsd, 164, n1, kb, lq);
                    if (kb & 1) { C01 = mf(a, b0f, C01); C11 = mf(a, b1f, C11); }
                    else        { C00 = mf(a, b0f, C00); C10 = mf(a, b1f, C10); }
                }
#pragma unroll
                for (int r = 0; r < 4; ++r) {
                    int m = 4 * lq + r;
                    sdbb[m * 136 + n0] = f2bf(ftanh(C00[r] + C01[r]));
                    sdbb[m * 136 + n1] = f2bf(ftanh(C10[r] + C11[r]));
                }
            }
            __syncthreads();

            // ================= SG (glu) =================
            {
                floatx4 C0 = z4, C1 = z4;
                int n0 = 32 * w + ln, n1 = n0 + 16;
#pragma unroll
                for (int kb = 0; kb < 4; ++kb) {
                    short8 a = ldA(sdbb, 68, ln, kb, lq);
                    C0 = mf(a, Bsg[0][kb], C0);
                    C1 = mf(a, Bsg[1][kb], C1);
                }
#pragma unroll
                for (int r = 0; r < 4; ++r) {
                    int m = 4 * lq + r;
                    float s0 = bf2f(sdbb[m * 136 + n0]);
                    float s1 = bf2f(sdbb[m * 136 + n1]);
                    sobb[m * 136 + n0] = f2bf(s0 * fsig(C0[r]));
                    sobb[m * 136 + n1] = f2bf(s1 * fsig(C1[r]));
                }
            }
            __syncthreads();

            // ================= OUT (tanh) =================
            {
                floatx4 C = z4;
#pragma unroll
                for (int kb = 0; kb < 4; ++kb)
                    C = mf(ldA(sobb, 68, ln, kb, lq), Bout[kb], C);
#pragma unroll
                for (int r = 0; r < 4; ++r) {
                    int m = 4 * lq + r;
                    float ov = ftanh(C[r]);
                    hist[m * 520 + ((base + nj) & 511)] = f2bf(ov);
                    size_t oi = (size_t)(b0 + m) * (NFRAMES * NSUB * SS)
                              + f * (NSUB * SS) + kk * SS + nj;
                    if (f32) ((float*)outp)[oi] = ov;
                    else     ((unsigned short*)outp)[oi] = f2bf(ov);
                }
            }
            __syncthreads();

            base += SS;
        }
    }
}

// ---------- launch ----------
extern "C" void kernel_launch(void* const* d_in, const int* in_sizes, int n_in,
                              void* d_out, int out_size, void* d_ws, size_t ws_size,
                              hipStream_t stream) {
    const void* feats = d_in[0];
    const void* gfeat = d_in[1];
    const void* prev  = d_in[2];
    const void* Wc1   = d_in[3];
    const void* Wc2   = d_in[4];
    const void* Wc3   = d_in[5];
    const void* Wfw   = d_in[6];
    const void* Wfwg  = d_in[7];
    const void* Wih1  = d_in[8];
    const void* Whh1  = d_in[9];
    const void* Wih2  = d_in[10];
    const void* Whh2  = d_in[11];
    const void* Wih3  = d_in[12];
    const void* Whh3  = d_in[13];
    const void* Wg1   = d_in[14];
    const void* Wg2   = d_in[15];
    const void* Wg3   = d_in[16];
    const void* Wsg   = d_in[17];
    const void* Wsd   = d_in[18];
    const void* Wout  = d_in[19];

    int*          flag = (int*)d_ws;                                // 1 int @ 0
    float*        cbuf = (float*)((char*)d_ws + 256);               // 13,107,200 B
    unsigned int* wct  = (unsigned int*)((char*)d_ws + 256 + 13107200);  // 524,288 B

    fargan_detect<<<1, 1, 0, stream>>>(feats, flag);
    fargan_prep_conv<<<512, 256, 0, stream>>>(flag, Wc1, Wc2, Wc3, wct);
    fargan_conv<<<BATCH * NFRAMES, 256, 0, stream>>>(feats, gfeat, flag, wct, cbuf);
    fargan_seq<<<BATCH / RPW, 256, 0, stream>>>(feats, prev, Wfw, Wfwg,
                                                Wih1, Whh1, Wih2, Whh2, Wih3, Whh3,
                                                Wg1, Wg2, Wg3, Wsg, Wsd, Wout,
                                                flag, cbuf, d_out);
}

// Round 7
// 2618.367 us; speedup vs baseline: 8.9091x; 1.2963x over previous
//
#include <hip/hip_runtime.h>
#include <hip/hip_bf16.h>

// FARGAN vocoder on MI355X. Sizes fixed by the reference:
#define SS      64
#define NSUB    4
#define LPREV   512
#define NF      193
#define NFRAMES 100
#define BATCH   64
#define RPW     16     // batch rows per workgroup (MFMA M)

typedef __attribute__((ext_vector_type(8))) short   short8;   // 8 bf16 (4 VGPRs)
typedef __attribute__((ext_vector_type(4))) float   floatx4;  // MFMA C/D

// ---------- scalar helpers ----------
__device__ __forceinline__ float bf2f(unsigned short u) {
    return __uint_as_float(((unsigned int)u) << 16);
}
__device__ __forceinline__ unsigned short f2bf(float x) {
    unsigned int u = __float_as_uint(x);
    return (unsigned short)((u + 0x7fffu + ((u >> 16) & 1u)) >> 16);
}
__device__ __forceinline__ unsigned int packbf(float a, float b) {
    return (unsigned int)f2bf(a) | ((unsigned int)f2bf(b) << 16);
}
__device__ __forceinline__ float fexp2(float x) {
#if __has_builtin(__builtin_amdgcn_exp2f)
    return __builtin_amdgcn_exp2f(x);
#else
    return exp2f(x);
#endif
}
__device__ __forceinline__ float frcp(float x) {
#if __has_builtin(__builtin_amdgcn_rcpf)
    return __builtin_amdgcn_rcpf(x);
#else
    return 1.0f / x;
#endif
}
// sigmoid: rcp(1 + 2^(-x*log2e))  (~4 VALU, hw rcp/exp)
__device__ __forceinline__ float fsig(float x) {
    return frcp(1.0f + fexp2(-1.442695041f * x));
}
// tanh(x) = 2*sigmoid(2x) - 1   (~5 VALU; inf-safe: exp2->inf => rcp->0 => -1)
__device__ __forceinline__ float ftanh(float x) {
    return fmaf(2.0f, frcp(1.0f + fexp2(-2.885390082f * x)), -1.0f);
}
__device__ __forceinline__ float ld1f(int f32, const void* p, size_t i) {
    if (f32) return ((const float*)p)[i];
    return bf2f(((const unsigned short*)p)[i]);
}
__device__ __forceinline__ float lo16(unsigned int u) { return __uint_as_float(u << 16); }
__device__ __forceinline__ float hi16(unsigned int u) { return __uint_as_float(u & 0xffff0000u); }

// MFMA wrapper
__device__ __forceinline__ floatx4 mf(short8 a, short8 b, floatx4 c) {
    return __builtin_amdgcn_mfma_f32_16x16x32_bf16(a, b, c, 0, 0, 0);
}

// A-fragment from packed-bf16 LDS buffer: row m, k-block kb, quad q.
__device__ __forceinline__ short8 ldA(const unsigned short* buf, int strideU,
                                      int m, int kb, int q) {
    const unsigned int* p = (const unsigned int*)buf + m * strideU + kb * 16 + q * 4;
    uint4 u = *(const uint4*)p;
    return __builtin_bit_cast(short8, u);
}
// B-fragment from prepacked weight buffer
__device__ __forceinline__ short8 ldB(const uint4* __restrict__ w, int idx) {
    return __builtin_bit_cast(short8, w[idx]);
}

// ---------- wbuf layout (units = 16B frags) ----------
// frag(seg, tile, kb, lane) at base + (tile*KB + kb)*64 + lane,
// lane = 16*lq + ln holds W[row = rowOff + tile*16 + ln][k = kb*32 + lq*8 .. +7]
#define OFF_FW   0        // 4t x 13kb
#define OFF_FWG  3328     // 4t x 2kb
#define OFF_GRU(G) (3840 + 4608*(G))   // r@+0(6kb) z@+1536(6kb) i@+3072(4kb) h@+4096(2kb)
#define OFF_WG(G)  (17664 + 512*(G))   // 4t x 2kb
#define OFF_SD   19200    // 8t x 10kb
#define OFF_SG   24320    // 8t x 4kb
#define OFF_OUT  26368    // 4t x 4kb
#define NFRAG    27392

// ---------- dtype detector ----------
// features[0,192,f] (period) in [64,300): 50/50 in-range as fp32 => fp32 inputs.
__global__ void fargan_detect(const void* feats, int* flag) {
    const float* pf = (const float*)feats;
    int ok = 1;
    for (int f = 0; f < 50; ++f) {
        float v = pf[192 * NFRAMES + f];
        if (!(v >= 63.0f && v <= 301.0f)) { ok = 0; break; }
    }
    *flag = ok;
}

// ---------- weight prep: repack all seq weights into frag order ----------
__global__ __launch_bounds__(256) void fargan_prep(
    const int* __restrict__ flag,
    const void* Wfw, const void* Wfwg,
    const void* Wih1, const void* Whh1, const void* Wih2, const void* Whh2,
    const void* Wih3, const void* Whh3,
    const void* Wg1, const void* Wg2, const void* Wg3,
    const void* Wsg, const void* Wsd, const void* Wout,
    uint4* __restrict__ wbuf)
{
    int fi = blockIdx.x * 256 + threadIdx.x;
    if (fi >= NFRAG) return;
    int f32 = *flag;
    const void* mats[14] = {Wfw, Wfwg, Wih1, Whh1, Wih2, Whh2, Wih3, Whh3,
                            Wg1, Wg2, Wg3, Wsg, Wsd, Wout};
    const int NSEG = 20;
    const int sb[NSEG]  = {0,3328, 3840,5376,6912,7936, 8448,9984,11520,12544,
                           13056,14592,16128,17152, 17664,18176,18688, 19200,24320,26368};
    const int sa[NSEG]  = {0,1, 2,2,2,3, 4,4,4,5, 6,6,6,7, 8,9,10, 12,11,13};
    const int sbx[NSEG] = {-1,-1, 3,3,-1,-1, 5,5,-1,-1, 7,7,-1,-1, -1,-1,-1, -1,-1,-1};
    const int sro[NSEG] = {0,0, 0,64,128,128, 0,64,128,128, 0,64,128,128, 0,0,0, 0,0,0};
    const int skb[NSEG] = {13,2, 6,6,4,2, 6,6,4,2, 6,6,4,2, 2,2,2, 10,4,4};
    const int ska[NSEG] = {388,64, 128,128,128,64, 128,128,128,64, 128,128,128,64,
                           64,64,64, 320,128,128};
    const int skr[NSEG] = {388,64, 192,192,128,64, 192,192,128,64, 192,192,128,64,
                           64,64,64, 320,128,128};
    int s = 0;
    for (int i = 1; i < NSEG; ++i) if (fi >= sb[i]) s = i;
    int local = fi - sb[s];
    int ln = local & 15, lq = (local >> 4) & 3, tkb = local >> 6;
    int KB = skb[s];
    int kb = tkb % KB, tile = tkb / KB;
    int row = sro[s] + tile * 16 + ln;
    int Ka = ska[s], Kr = skr[s];
    union { unsigned short h[8]; uint4 v; } u;
#pragma unroll
    for (int j = 0; j < 8; ++j) {
        int k = kb * 32 + lq * 8 + j;
        unsigned short val = 0;
        if (k < Kr) {
            const void* m; size_t off;
            if (sbx[s] >= 0 && k >= Ka) { m = mats[sbx[s]]; off = (size_t)row * 64 + (k - Ka); }
            else                        { m = mats[sa[s]];  off = (size_t)row * Ka + k; }
            val = f32 ? f2bf(((const float*)m)[off]) : ((const unsigned short*)m)[off];
        }
        u.h[j] = val;
    }
    wbuf[fi] = u.v;
}

// ---------- prep: repack Wc1/2/3 transposed + bf16-pair packed ----------
// wct layout (uints): L1 [k2<128][n<256] @0 ; L2 @32768 ; L3 [k2<128][n<512] @65536
__global__ __launch_bounds__(256) void fargan_prep_conv(
    const int* __restrict__ flag,
    const void* Wc1, const void* Wc2, const void* Wc3,
    unsigned int* __restrict__ wct)
{
    int idx = blockIdx.x * 256 + threadIdx.x;
    if (idx >= 131072) return;
    int f32 = *flag;
    const void* W; int n, k2;
    if (idx < 32768)      { W = Wc1; k2 = idx >> 8, n = idx & 255; }
    else if (idx < 65536) { W = Wc2; k2 = (idx - 32768) >> 8; n = idx & 255; }
    else                  { W = Wc3; k2 = (idx - 65536) >> 9; n = (idx - 65536) & 511; }
    size_t off = (size_t)n * 256 + 2 * k2;
    unsigned int v;
    if (f32) {
        const float* p = (const float*)W + off;
        v = packbf(p[0], p[1]);
    } else {
        v = *(const unsigned int*)((const unsigned short*)W + off);
    }
    wct[idx] = v;
}

// ---------- kernel 1: frame conv (coalesced transposed weights) ----------
template<bool F32>
__device__ __forceinline__ void conv_body(
    const void* __restrict__ feats, const void* __restrict__ gfeat,
    const unsigned int* __restrict__ wct, float* __restrict__ cbuf)
{
    int blk = blockIdx.x;
    int b = blk / NFRAMES, f = blk - b * NFRAMES;
    int t = threadIdx.x;
    __shared__ float xa[256], xb[256];

    float v;
    if (t < 192) v = ld1f(F32 ? 1 : 0, feats, (size_t)b * (NF * NFRAMES) + t * NFRAMES + f);
    else         v = ld1f(F32 ? 1 : 0, gfeat, (size_t)b * 64 + (t - 192));
    xa[t] = v;
    __syncthreads();

    const unsigned int* w1 = wct;
    const unsigned int* w2 = wct + 32768;
    const unsigned int* w3 = wct + 65536;

    float a0 = 0.f, a1 = 0.f;
#pragma unroll 8
    for (int k2 = 0; k2 < 128; ++k2) {
        unsigned int u = w1[k2 * 256 + t];
        a0 = fmaf(lo16(u), xa[2 * k2], a0);
        a1 = fmaf(hi16(u), xa[2 * k2 + 1], a1);
    }
    xb[t] = ftanh(a0 + a1);
    __syncthreads();

    a0 = 0.f; a1 = 0.f;
#pragma unroll 8
    for (int k2 = 0; k2 < 128; ++k2) {
        unsigned int u = w2[k2 * 256 + t];
        a0 = fmaf(lo16(u), xb[2 * k2], a0);
        a1 = fmaf(hi16(u), xb[2 * k2 + 1], a1);
    }
    xa[t] = ftanh(a0 + a1);
    __syncthreads();

    a0 = 0.f; a1 = 0.f;
    float b0 = 0.f, b1 = 0.f;
#pragma unroll 8
    for (int k2 = 0; k2 < 128; ++k2) {
        unsigned int u = w3[k2 * 512 + t];
        unsigned int u2 = w3[k2 * 512 + t + 256];
        a0 = fmaf(lo16(u),  xa[2 * k2],     a0);
        a1 = fmaf(hi16(u),  xa[2 * k2 + 1], a1);
        b0 = fmaf(lo16(u2), xa[2 * k2],     b0);
        b1 = fmaf(hi16(u2), xa[2 * k2 + 1], b1);
    }
    float* co = cbuf + ((size_t)b * NFRAMES + f) * 512;
    // transposed: element e (= j*4+k) -> co[k*128 + j]
    int e0 = t, e1 = t + 256;
    co[(e0 & 3) * 128 + (e0 >> 2)] = ftanh(a0 + a1);
    co[(e1 & 3) * 128 + (e1 >> 2)] = ftanh(b0 + b1);
}

__global__ __launch_bounds__(256) void fargan_conv(
    const void* feats, const void* gfeat,
    const int* flag, const unsigned int* wct, float* cbuf)
{
    if (*flag) conv_body<true>(feats, gfeat, wct, cbuf);
    else       conv_body<false>(feats, gfeat, wct, cbuf);
}

// ---------- kernel 2: sequential recurrence (MFMA, resident weights) ----------
// 4 WGs x 16 batch rows, 4 waves n-split. GRU states in C-layout registers;
// crow/period prefetched; prev_sub written directly from OUT epilogue;
// B-frags preloaded coalesced from prepacked wbuf.

__global__ __launch_bounds__(256, 1) void fargan_seq(
    const void* __restrict__ feats, const void* __restrict__ prev_in,
    const int* __restrict__ flag, const float* __restrict__ cbuf,
    const uint4* __restrict__ wbuf, void* __restrict__ outp)
{
    const int t = threadIdx.x;
    const int b0 = blockIdx.x * RPW;
    const int lane = t & 63, w = t >> 6;
    const int lq = lane >> 4, ln = lane & 15;
    const int nj = 16 * w + ln;            // n for 64-wide layers
    const int f32 = *flag;

    // ---- LDS ----
    __shared__ __align__(16) unsigned short hist[RPW * 520];   // bf16 ring, mod-512
    __shared__ __align__(16) unsigned short catb[RPW * 424];   // [feat2s|ps|look|sfw|0pad]
    __shared__ __align__(16) unsigned short xg  [RPW * 200];   // [in0|ps|s]
    __shared__ __align__(16) unsigned short skx [RPW * 328];   // [o1|o2|o3|fw|ps]
    __shared__ __align__(16) unsigned short sdbb[RPW * 136];
    __shared__ __align__(16) unsigned short sobb[RPW * 136];
    __shared__ __align__(16) unsigned short vpre[RPW * 72];
    __shared__ __align__(16) unsigned short svp [RPW * 72];    // packed s_new
    __shared__ __align__(16) unsigned short wsd[128 * 328];    // Wsd, 164u stride
    __shared__ int period_s[RPW];

    // ---- resident B-fragments, coalesced preload from wbuf ----
    short8 Bfw[13], Bfwg[2], Bout[4];
    short8 Br[3][6], Bz[3][6], Bi[3][4], Bh[3][2], Bg[3][2];
    short8 Bsg[2][4];
#pragma unroll
    for (int kb = 0; kb < 13; ++kb) Bfw[kb] = ldB(wbuf, OFF_FW + (w * 13 + kb) * 64 + lane);
#pragma unroll
    for (int kb = 0; kb < 2; ++kb)  Bfwg[kb] = ldB(wbuf, OFF_FWG + (w * 2 + kb) * 64 + lane);
#pragma unroll
    for (int G = 0; G < 3; ++G) {
        const int OR = OFF_GRU(G), OZ = OR + 1536, OI = OR + 3072, OH = OR + 4096;
#pragma unroll
        for (int kb = 0; kb < 6; ++kb) {
            Br[G][kb] = ldB(wbuf, OR + (w * 6 + kb) * 64 + lane);
            Bz[G][kb] = ldB(wbuf, OZ + (w * 6 + kb) * 64 + lane);
        }
#pragma unroll
        for (int kb = 0; kb < 4; ++kb) Bi[G][kb] = ldB(wbuf, OI + (w * 4 + kb) * 64 + lane);
#pragma unroll
        for (int kb = 0; kb < 2; ++kb) {
            Bh[G][kb] = ldB(wbuf, OH + (w * 2 + kb) * 64 + lane);
            Bg[G][kb] = ldB(wbuf, OFF_WG(G) + (w * 2 + kb) * 64 + lane);
        }
    }
#pragma unroll
    for (int tile = 0; tile < 2; ++tile)
#pragma unroll
        for (int kb = 0; kb < 4; ++kb)
            Bsg[tile][kb] = ldB(wbuf, OFF_SG + ((2 * w + tile) * 4 + kb) * 64 + lane);
#pragma unroll
    for (int kb = 0; kb < 4; ++kb) Bout[kb] = ldB(wbuf, OFF_OUT + (w * 4 + kb) * 64 + lane);

    // ---- Wsd -> LDS from wbuf (coalesced read, frag-order write) ----
    for (int fi = t; fi < 8 * 10 * 64; fi += 256) {
        int lane2 = fi & 63, tkb = fi >> 6;      // tkb = tile*10 + kb
        int kb = tkb % 10, tile = tkb / 10;
        int lq2 = lane2 >> 4, ln2 = lane2 & 15;
        int row = tile * 16 + ln2;
        uint4 v = wbuf[OFF_SD + fi];
        *(uint4*)((unsigned int*)wsd + row * 164 + kb * 16 + lq2 * 4) = v;
    }

    // ---- zero init LDS state + hist fill ----
    for (int i = t; i < RPW * 424; i += 256) catb[i] = 0;
    for (int i = t; i < RPW * 200; i += 256) xg[i] = 0;
    for (int i = t; i < RPW * 328; i += 256) skx[i] = 0;
    for (int i = t; i < RPW * 136; i += 256) { sdbb[i] = 0; sobb[i] = 0; }
    for (int i = t; i < RPW * 72;  i += 256) { vpre[i] = 0; svp[i] = 0; }
    for (int i = t; i < RPW * 512; i += 256) {
        int row = i >> 9, c = i & 511;
        hist[row * 520 + c] = f2bf(ld1f(f32, prev_in, (size_t)(b0 + row) * LPREV + c));
    }
    __syncthreads();
    // initial prev_sub slots (step 0): window[448..511] of prev_in
    for (int i = t; i < RPW * 64; i += 256) {
        int row = i >> 6, c = i & 63;
        unsigned short h = hist[row * 520 + 448 + c];
        catb[row * 424 + 128 + c] = h;
        skx [row * 328 + 256 + c] = h;
        xg  [row * 200 + 64  + c] = h;
    }

    // GRU states in C-layout registers: svr[G][r] = s[row 4lq+r][col nj]
    floatx4 svr[3];
#pragma unroll
    for (int G = 0; G < 3; ++G) svr[G] = (floatx4){0.f, 0.f, 0.f, 0.f};

    // ---- prefetch regs ----
    const int prow = t >> 4, px16 = t & 15, pe8 = (t & 15) * 8;
    float pfc[8];
    {
        const float* cr0 = cbuf + ((size_t)(b0 + prow) * NFRAMES + 0) * 512 + 0 * 128 + pe8;
#pragma unroll
        for (int i = 0; i < 8; ++i) pfc[i] = cr0[i];
    }
    float pper = 0.f;
    if (t < RPW)
        pper = ld1f(f32, feats, (size_t)(b0 + t) * (NF * NFRAMES) + (NF - 1) * NFRAMES + 0);
    __syncthreads();

    const floatx4 z4 = {0.f, 0.f, 0.f, 0.f};
    int base = 0;
    for (int f = 0; f < NFRAMES; ++f) {
        if (t < RPW) period_s[t] = (int)rintf(pper);
        __syncthreads();
        if (t < RPW) {
            int fN = (f + 1 < NFRAMES) ? f + 1 : f;
            pper = ld1f(f32, feats, (size_t)(b0 + t) * (NF * NFRAMES) + (NF - 1) * NFRAMES + fN);
        }

        for (int kk = 0; kk < NSUB; ++kk) {
            // ================= BUILD (feat2s shuffle + lookback) =================
            {
                int row = prow;
                unsigned int* cat32 = (unsigned int*)catb;
                int cb = row * 212;
                int e8 = pe8;
                // old feat2s -> sfw slot [260:388)
                unsigned int o0 = cat32[cb + (e8 >> 1) + 0];
                unsigned int o1 = cat32[cb + (e8 >> 1) + 1];
                unsigned int o2 = cat32[cb + (e8 >> 1) + 2];
                unsigned int o3 = cat32[cb + (e8 >> 1) + 3];
                cat32[cb + 130 + (e8 >> 1) + 0] = o0;
                cat32[cb + 130 + (e8 >> 1) + 1] = o1;
                cat32[cb + 130 + (e8 >> 1) + 2] = o2;
                cat32[cb + 130 + (e8 >> 1) + 3] = o3;
                cat32[cb + (e8 >> 1) + 0] = packbf(pfc[0], pfc[1]);
                cat32[cb + (e8 >> 1) + 1] = packbf(pfc[2], pfc[3]);
                cat32[cb + (e8 >> 1) + 2] = packbf(pfc[4], pfc[5]);
                cat32[cb + (e8 >> 1) + 3] = packbf(pfc[6], pfc[7]);
                // prefetch next step's crow
                {
                    int sN = f * 4 + kk + 1;
                    if (sN > NFRAMES * 4 - 1) sN = NFRAMES * 4 - 1;
                    int fN = sN >> 2, kN = sN & 3;
                    const float* nc = cbuf + ((size_t)(b0 + row) * NFRAMES + fN) * 512
                                    + kN * 128 + e8;
#pragma unroll
                    for (int i = 0; i < 8; ++i) pfc[i] = nc[i];
                }
                // lookback -> cat[192:260)
                int per = period_s[row];
#pragma unroll
                for (int ii = 0; ii < 5; ++ii) {
                    int i = px16 * 5 + ii;
                    if (i < 68) {
                        int idx = LPREV - per + i - 2;
                        if (idx >= LPREV) idx -= per;
                        catb[row * 424 + 192 + i] = hist[row * 520 + ((base + idx) & 511)];
                    }
                }
            }
            __syncthreads();

            // ================= FW (tanh), 2 chains =================
            {
                floatx4 C0 = z4, C1 = z4;
#pragma unroll
                for (int kb = 0; kb < 13; ++kb) {
                    short8 a = ldA(catb, 212, ln, kb, lq);
                    if (kb & 1) C1 = mf(a, Bfw[kb], C1);
                    else        C0 = mf(a, Bfw[kb], C0);
                }
#pragma unroll
                for (int r = 0; r < 4; ++r) {
                    int m = 4 * lq + r;
                    vpre[m * 72 + nj] = f2bf(ftanh(C0[r] + C1[r]));
                }
            }
            __syncthreads();

            // ================= FWG (glu); also stage sv[0] =================
            {
                floatx4 C = z4;
#pragma unroll
                for (int kb = 0; kb < 2; ++kb)
                    C = mf(ldA(vpre, 36, ln, kb, lq), Bfwg[kb], C);
#pragma unroll
                for (int r = 0; r < 4; ++r) {
                    int m = 4 * lq + r;
                    float vp = bf2f(vpre[m * 72 + nj]);
                    unsigned short ob = f2bf(vp * fsig(C[r]));
                    skx[m * 328 + 192 + nj] = ob;   // fw slot
                    xg [m * 200 + nj]       = ob;   // in0 for GRU1
                    xg [m * 200 + 128 + nj] = f2bf(svr[0][r]);   // s for GRU1
                }
            }
            __syncthreads();

            // ================= GRU + GLU x3 =================
#pragma unroll
            for (int G = 0; G < 3; ++G) {
                // GRU dot + in-lane nonlinearity (4 independent chains)
                {
                    floatx4 Cr = z4, Cz = z4, Ci = z4, Ch = z4;
#pragma unroll
                    for (int kb = 0; kb < 6; ++kb) {
                        short8 a = ldA(xg, 100, ln, kb, lq);
                        Cr = mf(a, Br[G][kb], Cr);
                        Cz = mf(a, Bz[G][kb], Cz);
                        if (kb < 4) Ci = mf(a, Bi[G][kb], Ci);
                        else        Ch = mf(a, Bh[G][kb - 4], Ch);
                    }
#pragma unroll
                    for (int r = 0; r < 4; ++r) {
                        int m = 4 * lq + r;
                        float rr = fsig(Cr[r]);
                        float zz = fsig(Cz[r]);
                        float nn = ftanh(Ci[r] + rr * Ch[r]);
                        float sn = fmaf(zz, svr[G][r] - nn, nn);
                        svr[G][r] = sn;
                        svp[m * 72 + nj] = f2bf(sn);
                    }
                }
                __syncthreads();
                // GLU on s_new; stage next GRU's in0 + s
                {
                    floatx4 C = z4;
#pragma unroll
                    for (int kb = 0; kb < 2; ++kb)
                        C = mf(ldA(svp, 36, ln, kb, lq), Bg[G][kb], C);
#pragma unroll
                    for (int r = 0; r < 4; ++r) {
                        int m = 4 * lq + r;
                        unsigned short ob = f2bf(svr[G][r] * fsig(C[r]));
                        skx[m * 328 + G * 64 + nj] = ob;
                        if (G < 2) {
                            xg[m * 200 + nj]       = ob;                  // in0
                            xg[m * 200 + 128 + nj] = f2bf(svr[G + 1][r]); // s
                        }
                    }
                }
                __syncthreads();
            }

            // ================= SD (tanh), B from LDS, 4 chains =================
            {
                floatx4 C00 = z4, C01 = z4, C10 = z4, C11 = z4;
                int n0 = 32 * w + ln, n1 = n0 + 16;
#pragma unroll
                for (int kb = 0; kb < 10; ++kb) {
                    short8 a   = ldA(skx, 164, ln, kb, lq);
                    short8 b0f = ldA(wsd, 164, n0, kb, lq);
                    short8 b1f = ldA(wsd, 164, n1, kb, lq);
                    if (kb & 1) { C01 = mf(a, b0f, C01); C11 = mf(a, b1f, C11); }
                    else        { C00 = mf(a, b0f, C00); C10 = mf(a, b1f, C10); }
                }
#pragma unroll
                for (int r = 0; r < 4; ++r) {
                    int m = 4 * lq + r;
                    sdbb[m * 136 + n0] = f2bf(ftanh(C00[r] + C01[r]));
                    sdbb[m * 136 + n1] = f2bf(ftanh(C10[r] + C11[r]));
                }
            }
            __syncthreads();

            // ================= SG (glu) =================
            {
                floatx4 C0 = z4, C1 = z4;
                int n0 = 32 * w + ln, n1 = n0 + 16;
#pragma unroll
                for (int kb = 0; kb < 4; ++kb) {
                    short8 a = ldA(sdbb, 68, ln, kb, lq);
                    C0 = mf(a, Bsg[0][kb], C0);
                    C1 = mf(a, Bsg[1][kb], C1);
                }
#pragma unroll
                for (int r = 0; r < 4; ++r) {
                    int m = 4 * lq + r;
                    float s0 = bf2f(sdbb[m * 136 + n0]);
                    float s1 = bf2f(sdbb[m * 136 + n1]);
                    sobb[m * 136 + n0] = f2bf(s0 * fsig(C0[r]));
                    sobb[m * 136 + n1] = f2bf(s1 * fsig(C1[r]));
                }
            }
            __syncthreads();

            // ================= OUT (tanh) + prev_sub fusion =================
            {
                floatx4 C = z4;
#pragma unroll
                for (int kb = 0; kb < 4; ++kb)
                    C = mf(ldA(sobb, 68, ln, kb, lq), Bout[kb], C);
#pragma unroll
                for (int r = 0; r < 4; ++r) {
                    int m = 4 * lq + r;
                    float ov = ftanh(C[r]);
                    unsigned short ob = f2bf(ov);
                    hist[m * 520 + ((base + nj) & 511)] = ob;
                    // next step's prev_sub IS this output
                    catb[m * 424 + 128 + nj] = ob;
                    skx [m * 328 + 256 + nj] = ob;
                    xg  [m * 200 + 64  + nj] = ob;
                    size_t oi = (size_t)(b0 + m) * (NFRAMES * NSUB * SS)
                              + f * (NSUB * SS) + kk * SS + nj;
                    if (f32) ((float*)outp)[oi] = ov;
                    else     ((unsigned short*)outp)[oi] = ob;
                }
            }
            __syncthreads();

            base += SS;
        }
    }
}

// ---------- launch ----------
extern "C" void kernel_launch(void* const* d_in, const int* in_sizes, int n_in,
                              void* d_out, int out_size, void* d_ws, size_t ws_size,
                              hipStream_t stream) {
    const void* feats = d_in[0];
    const void* gfeat = d_in[1];
    const void* prev  = d_in[2];
    const void* Wc1   = d_in[3];
    const void* Wc2   = d_in[4];
    const void* Wc3   = d_in[5];
    const void* Wfw   = d_in[6];
    const void* Wfwg  = d_in[7];
    const void* Wih1  = d_in[8];
    const void* Whh1  = d_in[9];
    const void* Wih2  = d_in[10];
    const void* Whh2  = d_in[11];
    const void* Wih3  = d_in[12];
    const void* Whh3  = d_in[13];
    const void* Wg1   = d_in[14];
    const void* Wg2   = d_in[15];
    const void* Wg3   = d_in[16];
    const void* Wsg   = d_in[17];
    const void* Wsd   = d_in[18];
    const void* Wout  = d_in[19];

    int*          flag = (int*)d_ws;                                     // 1 int @ 0
    float*        cbuf = (float*)((char*)d_ws + 256);                    // 13,107,200 B
    unsigned int* wct  = (unsigned int*)((char*)d_ws + 256 + 13107200);  // 524,288 B
    uint4*        wbuf = (uint4*)((char*)d_ws + 256 + 13107200 + 524288);// 438,272 B

    fargan_detect<<<1, 1, 0, stream>>>(feats, flag);
    fargan_prep<<<(NFRAG + 255) / 256, 256, 0, stream>>>(flag, Wfw, Wfwg,
        Wih1, Whh1, Wih2, Whh2, Wih3, Whh3, Wg1, Wg2, Wg3, Wsg, Wsd, Wout, wbuf);
    fargan_prep_conv<<<512, 256, 0, stream>>>(flag, Wc1, Wc2, Wc3, wct);
    fargan_conv<<<BATCH * NFRAMES, 256, 0, stream>>>(feats, gfeat, flag, wct, cbuf);
    fargan_seq<<<BATCH / RPW, 256, 0, stream>>>(feats, prev, flag, cbuf, wbuf, d_out);
}